// Round 11
// baseline (422.595 us; speedup 1.0000x reference)
//
#include <hip/hip_runtime.h>

typedef _Float16 f16;
typedef _Float16 f16x4 __attribute__((ext_vector_type(4)));
typedef _Float16 f16x8 __attribute__((ext_vector_type(8)));
typedef __fp16   h16x2 __attribute__((ext_vector_type(2)));
typedef float    f32x4 __attribute__((ext_vector_type(4)));

struct h16x2x2 { h16x2 lo, hi; };

#define MFMA16(a,b,c) __builtin_amdgcn_mfma_f32_16x16x32_f16((a),(b),(c),0,0,0)

#define LATENT 64
#define HIDDEN 128
#define ROWB  272          // LDS activation row pitch (17 x 16B)
#define ROWF  (ROWB / 2)

// LDS-only barrier (no vmcnt drain).
__device__ __forceinline__ void bar_lds() {
  asm volatile("s_waitcnt lgkmcnt(0)\n\ts_barrier" ::: "memory");
}
// Intra-wave LDS write->read fence.
__device__ __forceinline__ void fence_lds() {
  asm volatile("s_waitcnt lgkmcnt(0)" ::: "memory");
}
// Force a (possibly wave-uniform) float into a VGPR. Works around the backend
// emitting V_ADD_F32 with two SGPR operands (constant-bus violation) for
// uniform f32 arithmetic.
__device__ __forceinline__ float vgprf(float x) {
  float r;
  asm("v_mov_b32 %0, %1" : "=v"(r) : "v"(x));
  return r;
}

// A-fragment of W[out][K] (row-major f32) for out-tile `tile`, k-chunk kf.
__device__ __forceinline__ f16x8 load_afrag(const float* __restrict__ W, int K,
                                            int tile, int kf, int lane) {
  const int row = tile * 16 + (lane & 15);
  const int k0  = kf * 32 + (lane >> 4) * 8;
  const float* p = W + row * K + k0;
  f16x8 r;
#pragma unroll
  for (int j = 0; j < 8; ++j) r[j] = (f16)p[j];
  return r;
}

// B-fragment from LDS tile [16 rows][cols] (row = lane%16).
__device__ __forceinline__ f16x8 bfrag(const f16* buf, int k0, int lane) {
  const int b  = lane & 15;
  const int kk = k0 + (lane >> 4) * 8;
  return *(const f16x8*)((const char*)buf + b * ROWB + kk * 2);
}

// Write one D-tile (f32x4 -> f16x4, packed cvt) into an LDS tile.
__device__ __forceinline__ void dwrite(f16* buf, int dbase, f32x4 v, int lane) {
  const int b = lane & 15;
  h16x2x2 p;
  p.lo = __builtin_amdgcn_cvt_pkrtz(v[0], v[1]);
  p.hi = __builtin_amdgcn_cvt_pkrtz(v[2], v[3]);
  const f16x4 h = __builtin_bit_cast(f16x4, p);
  *(f16x4*)((char*)buf + b * ROWB + dbase * 2) = h;
}

__device__ __forceinline__ f32x4 elu4(f32x4 d) {
#pragma unroll
  for (int i = 0; i < 4; ++i) {
    const float e = __expf(d[i]) - 1.f;
    d[i] = d[i] > 0.f ? d[i] : e;
  }
  return d;
}

__global__ __launch_bounds__(256, 1)
void node_rk4_kernel(const float* __restrict__ z0,   const float* __restrict__ tg,
                     const float* __restrict__ fc1w, const float* __restrict__ fc1b,
                     const float* __restrict__ fc2w, const float* __restrict__ fc2b,
                     const float* __restrict__ fc3w, const float* __restrict__ fc3b,
                     const float* __restrict__ l2hw, const float* __restrict__ l2hb,
                     const float* __restrict__ h2ow, const float* __restrict__ h2ob,
                     float* __restrict__ out, int Btot, int T) {
  __shared__ __align__(16) f16 h1buf[16 * ROWF];  // h1 of current stage
  __shared__ __align__(16) f16 h2a[16 * ROWF];    // h2 ping
  __shared__ __align__(16) f16 h2b[16 * ROWF];    // h2 pong
  __shared__ __align__(16) f16 dch1[16 * ROWF];   // decoder hidden
  // composite weights W13=fc1*fc3^T, WL3=l2h*fc3^T as A-fragments:
  // layout [mat][tile][kf][lane] * 8 f16 (16B/lane, lane-contiguous)
  __shared__ __align__(16) f16 wlds[2 * 8 * 4 * 64 * 8];  // 64 KB

  const int tid  = threadIdx.x;
  const int lane = tid & 63;
  const int wv   = tid >> 6;   // owns hidden out-tiles {2wv, 2wv+1}, latent tile wv
  const int grp  = lane >> 4;
  const int bcol = lane & 15;
  const int row0 = blockIdx.x * 16;
  const f32x4 Z0 = {0.f, 0.f, 0.f, 0.f};

  auto wfrag = [&](int mat, int tile, int kf) -> f16x8 {
    return *(const f16x8*)(wlds + (((mat * 8 + tile) * 4 + kf) * 64 + lane) * 8);
  };
  auto wfrag_put = [&](int mat, int tile, int kf, f16x8 v) {
    *(f16x8*)(wlds + (((mat * 8 + tile) * 4 + kf) * 64 + lane) * 8) = v;
  };

  // ---------------- persistent register weights ----------------
  f16x8 a2[2][4], aO[4];
  f32x4 b2[2], bO;
#pragma unroll
  for (int ot = 0; ot < 2; ++ot) {
#pragma unroll
    for (int kf = 0; kf < 4; ++kf) a2[ot][kf] = load_afrag(fc2w, 128, 2 * wv + ot, kf, lane);
    b2[ot] = *(const f32x4*)(fc2b + (2 * wv + ot) * 16 + grp * 4);
  }
  const int dz = wv * 16 + grp * 4;
#pragma unroll
  for (int kf = 0; kf < 4; ++kf) aO[kf] = load_afrag(h2ow, 128, wv, kf, lane);
  bO = *(const f32x4*)(h2ob + dz);

  // ---------------- init: stage z0 (borrow h2a) ----------------
  {
    f32x4 zv = *(const f32x4*)(z0 + (size_t)(row0 + bcol) * LATENT + dz);
    dwrite(h2a, dz, zv, lane);
  }
  bar_lds();

  // init-only temporaries (die after W-build)
  f16x8 a1t[2][2], aLt[2][2];
  f32x4 b1t[2], bLt[2];
#pragma unroll
  for (int ot = 0; ot < 2; ++ot) {
#pragma unroll
    for (int kf = 0; kf < 2; ++kf) {
      a1t[ot][kf] = load_afrag(fc1w, 64, 2 * wv + ot, kf, lane);
      aLt[ot][kf] = load_afrag(l2hw, 64, 2 * wv + ot, kf, lane);
    }
    b1t[ot] = *(const f32x4*)(fc1b + (2 * wv + ot) * 16 + grp * 4);
    bLt[ot] = *(const f32x4*)(l2hb + (2 * wv + ot) * 16 + grp * 4);
  }

  // pre1 = fc1*z0 + b1 ; preL = l2h*z0 + bL   (persistent f32 state, D-layout)
  f32x4 pre1[2], preL[2];
  {
    const f16x8 zf0 = bfrag(h2a, 0, lane);
    const f16x8 zf1 = bfrag(h2a, 32, lane);
#pragma unroll
    for (int ot = 0; ot < 2; ++ot) {
      pre1[ot] = MFMA16(a1t[ot][1], zf1, MFMA16(a1t[ot][0], zf0, b1t[ot]));
      preL[ot] = MFMA16(aLt[ot][1], zf1, MFMA16(aLt[ot][0], zf0, bLt[ot]));
    }
  }
  bar_lds();  // z0 reads done before h2a reused as scratch

  // ---------------- v13 = fc1*fc3b, vL3 = l2h*fc3b ----------------
  f32x4 v13[2], vL3[2];
#pragma unroll
  for (int ot = 0; ot < 2; ++ot) {
#pragma unroll
    for (int r = 0; r < 4; ++r) {
      const int dimg = (2 * wv + ot) * 16 + grp * 4 + r;
      float s13 = 0.f, sL3 = 0.f;
      for (int l = 0; l < LATENT; l += 4) {
        const f32x4 bv = *(const f32x4*)(fc3b + l);
        const f32x4 w1 = *(const f32x4*)(fc1w + dimg * LATENT + l);
        const f32x4 wL = *(const f32x4*)(l2hw + dimg * LATENT + l);
#pragma unroll
        for (int q = 0; q < 4; ++q) { s13 += w1[q] * bv[q]; sL3 += wL[q] * bv[q]; }
      }
      v13[ot][r] = s13;
      vL3[ot][r] = sL3;
    }
  }

  // ---------------- build W13 / WL3 A-frags -> wlds ----------------
  f16* scr = wv == 0 ? h1buf : wv == 1 ? h2a : wv == 2 ? h2b : dch1;  // wave-private
#pragma unroll
  for (int m = 0; m < 2; ++m) {
#pragma unroll
    for (int ot = 0; ot < 2; ++ot) {
      for (int tj = 0; tj < 8; ++tj) {
        f16x8 bf0, bf1;
#pragma unroll
        for (int jj = 0; jj < 8; ++jj) {
          const int l0 = 8 * grp + jj;
          bf0[jj] = (f16)fc3w[l0 * HIDDEN + 16 * tj + bcol];
          bf1[jj] = (f16)fc3w[(32 + l0) * HIDDEN + 16 * tj + bcol];
        }
        f32x4 d;
        if (m == 0) d = MFMA16(a1t[ot][1], bf1, MFMA16(a1t[ot][0], bf0, Z0));
        else        d = MFMA16(aLt[ot][1], bf1, MFMA16(aLt[ot][0], bf0, Z0));
        // transpose-write D (col=bcol, row=4grp+r) -> scr[row][col]
#pragma unroll
        for (int r = 0; r < 4; ++r)
          scr[(4 * grp + r) * ROWF + 16 * tj + bcol] = (f16)d[r];
      }
      fence_lds();
#pragma unroll
      for (int kf = 0; kf < 4; ++kf)
        wfrag_put(m, 2 * wv + ot, kf, bfrag(scr, kf * 32, lane));
      fence_lds();
    }
  }
  bar_lds();  // wlds complete; scratch buffers return to pool

  // ---------------- helpers ----------------
  auto l2 = [&](f16* dst) {  // h1buf -> dst (fc2 + elu)
    f16x8 h[4];
#pragma unroll
    for (int kf = 0; kf < 4; ++kf) h[kf] = bfrag(h1buf, kf * 32, lane);
#pragma unroll
    for (int ot = 0; ot < 2; ++ot) {
      f32x4 c0 = MFMA16(a2[ot][0], h[0], b2[ot]);
      c0 = MFMA16(a2[ot][1], h[1], c0);
      f32x4 c1 = MFMA16(a2[ot][2], h[2], Z0);
      c1 = MFMA16(a2[ot][3], h[3], c1);
      f32x4 d = elu4(c0 + c1);
      dwrite(dst, (2 * wv + ot) * 16 + grp * 4, d, lane);
    }
  };

  f16x8 hs0, hs1, hs2, hs3;  // weighted h2 sum (B-frag layout, packed f16)

  // stage: read h2 from src, update hs, write h1 of next RK stage
  auto stageW = [&](const f16* src, float sc, int mode /*0:init 1:+2h*/) {
    f16x8 w[8];
#pragma unroll
    for (int q = 0; q < 8; ++q) w[q] = wfrag(0, 2 * wv + (q >> 2), q & 3);
    f16x8 h0 = bfrag(src, 0, lane),  h1f = bfrag(src, 32, lane);
    f16x8 h2f = bfrag(src, 64, lane), h3f = bfrag(src, 96, lane);
    if (mode == 0) { hs0 = h0; hs1 = h1f; hs2 = h2f; hs3 = h3f; }
    else { hs0 += h0 + h0; hs1 += h1f + h1f; hs2 += h2f + h2f; hs3 += h3f + h3f; }
#pragma unroll
    for (int ot = 0; ot < 2; ++ot) {
      f32x4 c0 = MFMA16(w[ot * 4 + 0], h0, v13[ot]);
      c0 = MFMA16(w[ot * 4 + 1], h1f, c0);
      f32x4 c1 = MFMA16(w[ot * 4 + 2], h2f, Z0);
      c1 = MFMA16(w[ot * 4 + 3], h3f, c1);
      f32x4 pk;
#pragma unroll
      for (int i = 0; i < 4; ++i) pk[i] = pre1[ot][i] + sc * (c0[i] + c1[i]);
      pk = elu4(pk);
      dwrite(h1buf, (2 * wv + ot) * 16 + grp * 4, pk, lane);
    }
  };

  // ---------------- main loop: 8 barrier segments / step ----------------
  float t_cur = vgprf(tg[0]);
  float t_nxt = vgprf(tg[1]);
  float dtp = 0.f, dt6p = 0.f;
  for (int s = 0;; ++s) {
    const bool last = (s == T - 1);

    // SEG_A: finalize pre's from prev step's hs, write dch1 (+h1 for k1)
    if (s > 0) {
      hs0 += bfrag(h2b, 0, lane);
      hs1 += bfrag(h2b, 32, lane);
      hs2 += bfrag(h2b, 64, lane);
      hs3 += bfrag(h2b, 96, lane);
      {
        f16x8 w[8];
#pragma unroll
        for (int q = 0; q < 8; ++q) w[q] = wfrag(0, 2 * wv + (q >> 2), q & 3);
#pragma unroll
        for (int ot = 0; ot < 2; ++ot) {
          f32x4 c0 = MFMA16(w[ot * 4 + 0], hs0, Z0);
          c0 = MFMA16(w[ot * 4 + 1], hs1, c0);
          f32x4 c1 = MFMA16(w[ot * 4 + 2], hs2, Z0);
          c1 = MFMA16(w[ot * 4 + 3], hs3, c1);
#pragma unroll
          for (int i = 0; i < 4; ++i) pre1[ot][i] += dt6p * (c0[i] + c1[i]) + dtp * v13[ot][i];
        }
      }
      {
        f16x8 w[8];
#pragma unroll
        for (int q = 0; q < 8; ++q) w[q] = wfrag(1, 2 * wv + (q >> 2), q & 3);
#pragma unroll
        for (int ot = 0; ot < 2; ++ot) {
          f32x4 d0 = MFMA16(w[ot * 4 + 0], hs0, Z0);
          d0 = MFMA16(w[ot * 4 + 1], hs1, d0);
          f32x4 d1 = MFMA16(w[ot * 4 + 2], hs2, Z0);
          d1 = MFMA16(w[ot * 4 + 3], hs3, d1);
#pragma unroll
          for (int i = 0; i < 4; ++i) preL[ot][i] += dt6p * (d0[i] + d1[i]) + dtp * vL3[ot][i];
        }
      }
    }
#pragma unroll
    for (int ot = 0; ot < 2; ++ot) {
      f32x4 d;
#pragma unroll
      for (int i = 0; i < 4; ++i) d[i] = fmaxf(preL[ot][i], 0.f);
      dwrite(dch1, (2 * wv + ot) * 16 + grp * 4, d, lane);
    }
    if (!last) {
#pragma unroll
      for (int ot = 0; ot < 2; ++ot) {
        f32x4 d = elu4(pre1[ot]);
        dwrite(h1buf, (2 * wv + ot) * 16 + grp * 4, d, lane);
      }
    }
    bar_lds();                                     // BAR1

    // SEG_B: decode + store ; l2 of k1
    {
      f16x8 hd[4];
#pragma unroll
      for (int kf = 0; kf < 4; ++kf) hd[kf] = bfrag(dch1, kf * 32, lane);
      f32x4 c0 = MFMA16(aO[0], hd[0], bO);
      c0 = MFMA16(aO[1], hd[1], c0);
      f32x4 c1 = MFMA16(aO[2], hd[2], Z0);
      c1 = MFMA16(aO[3], hd[3], c1);
      f32x4 o = c0 + c1;
      *(f32x4*)(out + ((size_t)s * Btot + row0 + bcol) * LATENT + dz) = o;
      if (last) break;
      l2(h2a);
    }
    bar_lds();                                     // BAR2

    const float t_fut = vgprf(tg[s + 2 < T ? s + 2 : T - 1]);
    const float dt = t_nxt - t_cur;
    const float hdt = 0.5f * dt;

    stageW(h2a, hdt, 0);   // SEG_C: k2 h1 ; hs = h2(k1)
    bar_lds();                                     // BAR3
    l2(h2b);               // SEG_D
    bar_lds();                                     // BAR4
    stageW(h2b, hdt, 1);   // SEG_E: k3 h1 ; hs += 2 h2(k2)
    bar_lds();                                     // BAR5
    l2(h2a);               // SEG_F
    bar_lds();                                     // BAR6
    stageW(h2a, dt, 1);    // SEG_G: k4 h1 ; hs += 2 h2(k3)
    bar_lds();                                     // BAR7
    l2(h2b);               // SEG_H  (h2(k4); consumed next SEG_A)
    bar_lds();                                     // BAR8

    dtp = dt;
    dt6p = dt * (1.f / 6.f);
    t_cur = t_nxt;
    t_nxt = t_fut;
  }
}

extern "C" void kernel_launch(void* const* d_in, const int* in_sizes, int n_in,
                              void* d_out, int out_size, void* d_ws, size_t ws_size,
                              hipStream_t stream) {
  const float* z0   = (const float*)d_in[0];
  const float* tg   = (const float*)d_in[1];
  const float* fc1w = (const float*)d_in[2];
  const float* fc1b = (const float*)d_in[3];
  const float* fc2w = (const float*)d_in[4];
  const float* fc2b = (const float*)d_in[5];
  const float* fc3w = (const float*)d_in[6];
  const float* fc3b = (const float*)d_in[7];
  const float* l2hw = (const float*)d_in[8];
  const float* l2hb = (const float*)d_in[9];
  const float* h2ow = (const float*)d_in[10];
  const float* h2ob = (const float*)d_in[11];
  float* out = (float*)d_out;

  const int Btot = in_sizes[0] / LATENT;  // 4096
  const int T    = in_sizes[1];           // 100

  dim3 grid(Btot / 16), block(256);
  node_rk4_kernel<<<grid, block, 0, stream>>>(z0, tg, fc1w, fc1b, fc2w, fc2b,
                                              fc3w, fc3b, l2hw, l2hb, h2ow, h2ob,
                                              out, Btot, T);
}

// Round 12
// 297.947 us; speedup vs baseline: 1.4184x; 1.4184x over previous
//
#include <hip/hip_runtime.h>

typedef _Float16 f16;
typedef _Float16 f16x4 __attribute__((ext_vector_type(4)));
typedef _Float16 f16x8 __attribute__((ext_vector_type(8)));
typedef __fp16   h16x2 __attribute__((ext_vector_type(2)));
typedef float    f32x4 __attribute__((ext_vector_type(4)));

struct h16x2x2 { h16x2 lo, hi; };

#define MFMA16(a,b,c) __builtin_amdgcn_mfma_f32_16x16x32_f16((a),(b),(c),0,0,0)

#define LATENT 64
#define HIDDEN 128
#define ROWB  272
#define ROWF  (ROWB / 2)   // 136 f16 per row

// Barrier that orders LDS only: waits this wave's ds ops, then s_barrier.
// No vmcnt drain -> global stores never block the barrier.
__device__ __forceinline__ void bar_lds() {
  asm volatile("s_waitcnt lgkmcnt(0)\n\ts_barrier" ::: "memory");
}

// A-fragment of W[out][K] for out-tile `tile`, k-chunk kf (32 wide).
// mfma_f32_16x16x32_f16 A layout: row = lane%16, k = kf*32 + 8*(lane/16)+j
__device__ __forceinline__ f16x8 load_afrag(const float* __restrict__ W, int K,
                                            int tile, int kf, int lane) {
  const int row = tile * 16 + (lane & 15);
  const int k0  = kf * 32 + (lane >> 4) * 8;
  const float* p = W + row * K + k0;
  f16x8 r;
#pragma unroll
  for (int j = 0; j < 8; ++j) r[j] = (f16)p[j];
  return r;
}

// B-fragment from LDS activation tile: row b = lane%16 (batch), linear cols.
__device__ __forceinline__ f16x8 bfrag(const f16* buf, int k0, int lane) {
  const int b  = lane & 15;
  const int kk = k0 + (lane >> 4) * 8;
  return *(const f16x8*)((const char*)buf + b * ROWB + kk * 2);
}

// Write one D-tile (f32x4 -> f16x4, packed RTZ cvt) into an activation buffer.
__device__ __forceinline__ void dwrite(f16* buf, int dbase, f32x4 v, int lane) {
  const int b = lane & 15;
  h16x2x2 p;
  p.lo = __builtin_amdgcn_cvt_pkrtz(v[0], v[1]);
  p.hi = __builtin_amdgcn_cvt_pkrtz(v[2], v[3]);
  const f16x4 h = __builtin_bit_cast(f16x4, p);
  *(f16x4*)((char*)buf + b * ROWB + dbase * 2) = h;
}

__device__ __forceinline__ f32x4 elu4(f32x4 d) {
#pragma unroll
  for (int i = 0; i < 4; ++i) {
    const float e = __expf(d[i]) - 1.f;
    d[i] = d[i] > 0.f ? d[i] : e;
  }
  return d;
}

__global__ __launch_bounds__(256, 2)
void node_rk4_kernel(const float* __restrict__ z0,   const float* __restrict__ tg,
                     const float* __restrict__ fc1w, const float* __restrict__ fc1b,
                     const float* __restrict__ fc2w, const float* __restrict__ fc2b,
                     const float* __restrict__ fc3w, const float* __restrict__ fc3b,
                     const float* __restrict__ l2hw, const float* __restrict__ l2hb,
                     const float* __restrict__ h2ow, const float* __restrict__ h2ob,
                     float* __restrict__ out, int Btot, int T) {
  __shared__ __align__(16) f16 xbuf[16 * ROWF];   // f-input / z staging
  __shared__ __align__(16) f16 h1buf[16 * ROWF];  // fc1 hidden
  __shared__ __align__(16) f16 h2buf[16 * ROWF];  // fc2 hidden
  __shared__ __align__(16) f16 dch1[16 * ROWF];   // decoder hidden (l2h)

  const int tid  = threadIdx.x;
  const int lane = tid & 63;
  const int wv   = tid >> 6;   // 0..3; owns hidden tiles {2wv,2wv+1}, latent tile wv
  const int grp  = lane >> 4;
  const int bcol = lane & 15;
  const int row0 = blockIdx.x * 16;
  const f32x4 Z0 = {0.f, 0.f, 0.f, 0.f};

  // ---- weights -> registers (per-wave slices) ----
  f16x8 a1[2][2], aL[2][2], a2[2][4], a3[4], aO[4];
  f32x4 b1[2], b2[2], bL[2], b3, bO;
#pragma unroll
  for (int ot = 0; ot < 2; ++ot) {
#pragma unroll
    for (int kf = 0; kf < 2; ++kf) {
      a1[ot][kf] = load_afrag(fc1w, 64, 2 * wv + ot, kf, lane);
      aL[ot][kf] = load_afrag(l2hw, 64, 2 * wv + ot, kf, lane);
    }
#pragma unroll
    for (int kf = 0; kf < 4; ++kf) a2[ot][kf] = load_afrag(fc2w, 128, 2 * wv + ot, kf, lane);
    const int d = (2 * wv + ot) * 16 + grp * 4;
    b1[ot] = *(const f32x4*)(fc1b + d);
    b2[ot] = *(const f32x4*)(fc2b + d);
    bL[ot] = *(const f32x4*)(l2hb + d);
  }
#pragma unroll
  for (int kf = 0; kf < 4; ++kf) {
    a3[kf] = load_afrag(fc3w, 128, wv, kf, lane);
    aO[kf] = load_afrag(h2ow, 128, wv, kf, lane);
  }
  const int dz = wv * 16 + grp * 4;
  b3 = *(const f32x4*)(fc3b + dz);
  bO = *(const f32x4*)(h2ob + dz);

  // ---- z state: lane holds z[row0+bcol][dz..dz+3] (D layout) ----
  f32x4 z = *(const f32x4*)(z0 + (size_t)(row0 + bcol) * LATENT + dz);

  // layer pieces (no internal barriers; caller places bar_lds between)
  auto l1 = [&](f16x8 v0, f16x8 v1) {     // xbuf frags -> h1buf (fc1+elu)
#pragma unroll
    for (int ot = 0; ot < 2; ++ot) {
      f32x4 d = MFMA16(a1[ot][0], v0, b1[ot]);
      d = MFMA16(a1[ot][1], v1, d);
      d = elu4(d);
      dwrite(h1buf, (2 * wv + ot) * 16 + grp * 4, d, lane);
    }
  };
  auto l2 = [&]() {                       // h1buf -> h2buf (fc2+elu)
    f16x8 h[4];
#pragma unroll
    for (int kf = 0; kf < 4; ++kf) h[kf] = bfrag(h1buf, kf * 32, lane);
#pragma unroll
    for (int ot = 0; ot < 2; ++ot) {
      f32x4 c0 = MFMA16(a2[ot][0], h[0], b2[ot]);
      c0 = MFMA16(a2[ot][1], h[1], c0);
      f32x4 c1 = MFMA16(a2[ot][2], h[2], Z0);
      c1 = MFMA16(a2[ot][3], h[3], c1);
      f32x4 d = elu4(c0 + c1);
      dwrite(h2buf, (2 * wv + ot) * 16 + grp * 4, d, lane);
    }
  };
  auto l3 = [&]() -> f32x4 {              // h2buf -> k (fc3, own 16 latent dims)
    f16x8 g[4];
#pragma unroll
    for (int kf = 0; kf < 4; ++kf) g[kf] = bfrag(h2buf, kf * 32, lane);
    f32x4 c0 = MFMA16(a3[0], g[0], b3);
    c0 = MFMA16(a3[1], g[1], c0);
    f32x4 c1 = MFMA16(a3[2], g[2], Z0);
    c1 = MFMA16(a3[3], g[3], c1);
    return c0 + c1;
  };
  auto dec2_store = [&](int s) {          // dch1 -> h2o -> global store
    f16x8 hd[4];
#pragma unroll
    for (int kf = 0; kf < 4; ++kf) hd[kf] = bfrag(dch1, kf * 32, lane);
    f32x4 c0 = MFMA16(aO[0], hd[0], bO);
    c0 = MFMA16(aO[1], hd[1], c0);
    f32x4 c1 = MFMA16(aO[2], hd[2], Z0);
    c1 = MFMA16(aO[3], hd[3], c1);
    f32x4 o = c0 + c1;
    *(f32x4*)(out + ((size_t)s * Btot + row0 + bcol) * LATENT + dz) = o;
  };

  // prologue: stage z_0
  dwrite(xbuf, dz, z, lane);
  bar_lds();

  float t_cur = tg[0];
  float t_nxt = tg[1];
  for (int s = 0;; ++s) {
    const bool last = (s == T - 1);

    // SEG1: dec-l1 (l2h+relu) + k1-l1 — both consume xbuf
    {
      const f16x8 x0 = bfrag(xbuf, 0, lane);
      const f16x8 x1 = bfrag(xbuf, 32, lane);
#pragma unroll
      for (int ot = 0; ot < 2; ++ot) {
        f32x4 d = MFMA16(aL[ot][0], x0, bL[ot]);
        d = MFMA16(aL[ot][1], x1, d);
#pragma unroll
        for (int i = 0; i < 4; ++i) d[i] = fmaxf(d[i], 0.f);
        dwrite(dch1, (2 * wv + ot) * 16 + grp * 4, d, lane);
      }
      if (!last) l1(x0, x1);
    }
    bar_lds();                                       // BAR1

    if (last) { dec2_store(s); break; }

    // SEG2: k1-l2 only (decode tail moved to SEG3)
    l2();
    bar_lds();                                       // BAR2

    const float t_fut = tg[s + 2 < T ? s + 2 : T - 1];
    const float dt = t_nxt - t_cur;
    f32x4 k, acc, xs;

    // SEG3: dec-l2 + store + k1-l3 + stage x(k2)  (dch1/h2buf reads overlap)
    dec2_store(s);
    k = l3();
    acc = k;
#pragma unroll
    for (int i = 0; i < 4; ++i) xs[i] = z[i] + 0.5f * dt * k[i];
    dwrite(xbuf, dz, xs, lane);
    bar_lds();                                       // BAR3

    // ---- k2 ----
    { const f16x8 x0 = bfrag(xbuf, 0, lane), x1 = bfrag(xbuf, 32, lane);
      l1(x0, x1); }
    bar_lds();                                       // BAR4
    l2();
    bar_lds();                                       // BAR5
    k = l3();
#pragma unroll
    for (int i = 0; i < 4; ++i) { acc[i] += 2.f * k[i]; xs[i] = z[i] + 0.5f * dt * k[i]; }
    dwrite(xbuf, dz, xs, lane);
    bar_lds();                                       // BAR6

    // ---- k3 ----
    { const f16x8 x0 = bfrag(xbuf, 0, lane), x1 = bfrag(xbuf, 32, lane);
      l1(x0, x1); }
    bar_lds();                                       // BAR7
    l2();
    bar_lds();                                       // BAR8
    k = l3();
#pragma unroll
    for (int i = 0; i < 4; ++i) { acc[i] += 2.f * k[i]; xs[i] = z[i] + dt * k[i]; }
    dwrite(xbuf, dz, xs, lane);
    bar_lds();                                       // BAR9

    // ---- k4 ----
    { const f16x8 x0 = bfrag(xbuf, 0, lane), x1 = bfrag(xbuf, 32, lane);
      l1(x0, x1); }
    bar_lds();                                       // BAR10
    l2();
    bar_lds();                                       // BAR11
    k = l3();
#pragma unroll
    for (int i = 0; i < 4; ++i) z[i] += (dt / 6.f) * (acc[i] + k[i]);
    dwrite(xbuf, dz, z, lane);
    bar_lds();                                       // BAR12

    t_cur = t_nxt;
    t_nxt = t_fut;
  }
}

extern "C" void kernel_launch(void* const* d_in, const int* in_sizes, int n_in,
                              void* d_out, int out_size, void* d_ws, size_t ws_size,
                              hipStream_t stream) {
  const float* z0   = (const float*)d_in[0];
  const float* tg   = (const float*)d_in[1];
  const float* fc1w = (const float*)d_in[2];
  const float* fc1b = (const float*)d_in[3];
  const float* fc2w = (const float*)d_in[4];
  const float* fc2b = (const float*)d_in[5];
  const float* fc3w = (const float*)d_in[6];
  const float* fc3b = (const float*)d_in[7];
  const float* l2hw = (const float*)d_in[8];
  const float* l2hb = (const float*)d_in[9];
  const float* h2ow = (const float*)d_in[10];
  const float* h2ob = (const float*)d_in[11];
  float* out = (float*)d_out;

  const int Btot = in_sizes[0] / LATENT;  // 4096
  const int T    = in_sizes[1];           // 100

  dim3 grid(Btot / 16), block(256);
  node_rk4_kernel<<<grid, block, 0, stream>>>(z0, tg, fc1w, fc1b, fc2w, fc2b,
                                              fc3w, fc3b, l2hw, l2hb, h2ow, h2ob,
                                              out, Btot, T);
}